// Round 4
// baseline (567.559 us; speedup 1.0000x reference)
//
#include <hip/hip_runtime.h>
#include <cmath>

#define CNUM 512
#define DNUM 128
#define BNUM 4096
#define EPSV 1e-5f

// ---- all intermediates in device globals: no d_ws dependence at all ----
__device__ float g_counts[CNUM];
__device__ float g_mean[CNUM * DNUM];
__device__ float g_lp[CNUM];
__device__ float g_G[DNUM * DNUM];
__device__ float g_P0[DNUM * DNUM];
__device__ float g_P[DNUM * DNUM];
__device__ float g_Pm[CNUM * DNUM];
__device__ float g_r[CNUM];
__device__ float g_q[BNUM];

// ---------------- zero the accumulated buffers (every call) ----------------
__global__ __launch_bounds__(256) void k_zero() {
    int idx = blockIdx.x * 256 + threadIdx.x;
    if (idx < CNUM / 4) ((float4*)g_counts)[idx] = make_float4(0, 0, 0, 0);
    if (idx < CNUM * DNUM / 4) ((float4*)g_mean)[idx] = make_float4(0, 0, 0, 0);
    if (idx < DNUM * DNUM / 4) ((float4*)g_G)[idx] = make_float4(0, 0, 0, 0);
}

// ---------------- counts + per-class sums (atomics) ----------------
__global__ __launch_bounds__(256) void k_count_sum(const float* __restrict__ z, const int* __restrict__ y, int B) {
    int g = blockIdx.x * 256 + threadIdx.x;
    if (g >= B * 32) return;
    int b = g >> 5, c4 = g & 31;
    int yy = y[b];
    float4 zv = ((const float4*)z)[(size_t)b * 32 + c4];
    float* dst = g_mean + (size_t)yy * DNUM + c4 * 4;
    atomicAdd(dst + 0, zv.x);
    atomicAdd(dst + 1, zv.y);
    atomicAdd(dst + 2, zv.z);
    atomicAdd(dst + 3, zv.w);
    if (c4 == 0) atomicAdd(g_counts + yy, 1.0f);
}

// ---------------- mean = sum/(n+eps); logprior ----------------
__global__ __launch_bounds__(256) void k_mean_prior(float logtot) {
    int idx = blockIdx.x * 256 + threadIdx.x;   // 65536 threads
    int c = idx >> 7;
    float cnt = g_counts[c] + EPSV;
    g_mean[idx] = g_mean[idx] / cnt;
    if (idx < CNUM) g_lp[idx] = logf(g_counts[idx] + EPSV) - logtot;
}

// ---------------- G = sum_b dz dz^T (split over blocks, atomic partials) ----------------
__global__ __launch_bounds__(256) void k_gram(const float* __restrict__ z, const int* __restrict__ y) {
    __shared__ float dzs[16][132];
    int tx = threadIdx.x & 15, ty = threadIdx.x >> 4;
    float acc[8][8] = {};
    int b0 = blockIdx.x * 128;
    for (int ch = 0; ch < 8; ++ch) {
        int gb = b0 + ch * 16 + ty;           // ty = sample-in-chunk, tx = 8-float segment
        int yy = y[gb];
        const float4* zp = (const float4*)(z + (size_t)gb * DNUM + tx * 8);
        const float4* mp = (const float4*)(g_mean + (size_t)yy * DNUM + tx * 8);
        float4 a0 = zp[0], a1 = zp[1], m0 = mp[0], m1 = mp[1];
        float* drow = &dzs[ty][tx * 8];
        drow[0] = a0.x - m0.x; drow[1] = a0.y - m0.y; drow[2] = a0.z - m0.z; drow[3] = a0.w - m0.w;
        drow[4] = a1.x - m1.x; drow[5] = a1.y - m1.y; drow[6] = a1.z - m1.z; drow[7] = a1.w - m1.w;
        __syncthreads();
        #pragma unroll
        for (int s = 0; s < 16; ++s) {
            const float4* pa = (const float4*)&dzs[s][ty * 8];
            const float4* pb = (const float4*)&dzs[s][tx * 8];
            float4 t0 = pa[0], t1 = pa[1];
            float4 u0 = pb[0], u1 = pb[1];
            float va[8] = {t0.x, t0.y, t0.z, t0.w, t1.x, t1.y, t1.z, t1.w};
            float vb[8] = {u0.x, u0.y, u0.z, u0.w, u1.x, u1.y, u1.z, u1.w};
            #pragma unroll
            for (int i = 0; i < 8; ++i)
                #pragma unroll
                for (int j = 0; j < 8; ++j)
                    acc[i][j] += va[i] * vb[j];
        }
        __syncthreads();
    }
    #pragma unroll
    for (int i = 0; i < 8; ++i)
        #pragma unroll
        for (int j = 0; j < 8; ++j)
            atomicAdd(&g_G[(size_t)(ty * 8 + i) * DNUM + tx * 8 + j], acc[i][j]);
}

// ---------------- pooled = 0.5(G+G^T)/total + eps*I ----------------
__global__ __launch_bounds__(256) void k_finalize(float invtot2) {
    int idx = blockIdx.x * 256 + threadIdx.x;   // 16384
    int i = idx >> 7, j = idx & 127;
    float v = (g_G[idx] + g_G[(size_t)j * DNUM + i]) * invtot2;
    if (i == j) v += EPSV;
    g_P0[idx] = v;
}

// ---------------- in-place Gauss-Jordan inverse, matrix in LDS ----------------
// Sweep verified symbolically on 2x2. Rank-1 phase writes only (i!=k, j!=k)
// while reading untouched pivot row/col; scaling phase barrier-isolated.
// No pivoting (SPD, cond ~2 by Marchenko-Pastur).
__global__ __launch_bounds__(1024) void k_inv() {
    __shared__ float A[DNUM][DNUM + 1];
    __shared__ float dsh;
    const int t = threadIdx.x;
    #pragma unroll
    for (int v = 0; v < 16; ++v) {
        int idx = t + v * 1024;
        A[idx >> 7][idx & 127] = g_P0[idx];
    }
    __syncthreads();
    for (int k = 0; k < DNUM; ++k) {
        if (t == 0) dsh = 1.0f / A[k][k];
        __syncthreads();
        float d = dsh;
        int i = t >> 3;
        int j0 = (t & 7) * 16;
        if (i != k) {
            float cik = A[i][k] * d;
            #pragma unroll
            for (int jj = 0; jj < 16; ++jj) {
                int j = j0 + jj;
                if (j != k) A[i][j] -= cik * A[k][j];
            }
        }
        __syncthreads();
        if (t < DNUM) {
            if (t != k) {
                A[k][t] *= d;       // pivot row scale
                A[t][k] *= -d;      // pivot col negate-scale
            } else {
                A[k][k] = d;
            }
        }
        __syncthreads();
    }
    #pragma unroll
    for (int v = 0; v < 16; ++v) {
        int idx = t + v * 1024;
        g_P[idx] = A[idx >> 7][idx & 127];
    }
}

// ---------------- Pm = mean @ P  (64 rows per block) ----------------
__global__ __launch_bounds__(256) void k_matP() {
    __shared__ float xs[64][132];
    int t = threadIdx.x;
    int row0 = blockIdx.x * 64;
    #pragma unroll
    for (int v = 0; v < 8; ++v) {            // FIXED: full 64x128 tile (2048 float4)
        int idx = t + v * 256;
        int r = idx >> 5, f4 = idx & 31;
        float4 val = ((const float4*)g_mean)[(size_t)(row0 + r) * 32 + f4];
        *(float4*)&xs[r][f4 * 4] = val;
    }
    __syncthreads();
    int tx = t & 31, ty = t >> 5;                 // cols tx*4, rows ty*8
    float acc[8][4] = {};
    for (int e = 0; e < DNUM; ++e) {
        float4 pv = ((const float4*)g_P)[e * 32 + tx];
        #pragma unroll
        for (int i = 0; i < 8; ++i) {
            float xv = xs[ty * 8 + i][e];
            acc[i][0] += xv * pv.x; acc[i][1] += xv * pv.y;
            acc[i][2] += xv * pv.z; acc[i][3] += xv * pv.w;
        }
    }
    #pragma unroll
    for (int i = 0; i < 8; ++i)
        *(float4*)&g_Pm[(size_t)(row0 + ty * 8 + i) * DNUM + tx * 4] =
            make_float4(acc[i][0], acc[i][1], acc[i][2], acc[i][3]);
}

// ---------------- q_b = z_b . (P z_b), fused X@P + row-dot, no W store ----------------
__global__ __launch_bounds__(256) void k_q(const float* __restrict__ X) {
    __shared__ float xs[64][132];
    __shared__ float part[64][33];
    int t = threadIdx.x;
    int row0 = blockIdx.x * 64;
    #pragma unroll
    for (int v = 0; v < 8; ++v) {            // FIXED: full 64x128 tile (2048 float4)
        int idx = t + v * 256;
        int r = idx >> 5, f4 = idx & 31;
        float4 val = ((const float4*)X)[(size_t)(row0 + r) * 32 + f4];
        *(float4*)&xs[r][f4 * 4] = val;
    }
    __syncthreads();
    int tx = t & 31, ty = t >> 5;
    float acc[8][4] = {};
    for (int e = 0; e < DNUM; ++e) {
        float4 pv = ((const float4*)g_P)[e * 32 + tx];
        #pragma unroll
        for (int i = 0; i < 8; ++i) {
            float xv = xs[ty * 8 + i][e];
            acc[i][0] += xv * pv.x; acc[i][1] += xv * pv.y;
            acc[i][2] += xv * pv.z; acc[i][3] += xv * pv.w;
        }
    }
    #pragma unroll
    for (int i = 0; i < 8; ++i) {
        int r = ty * 8 + i;
        float s = acc[i][0] * xs[r][tx * 4 + 0] + acc[i][1] * xs[r][tx * 4 + 1]
                + acc[i][2] * xs[r][tx * 4 + 2] + acc[i][3] * xs[r][tx * 4 + 3];
        part[r][tx] = s;
    }
    __syncthreads();
    if (t < 64) {
        float s = 0.f;
        #pragma unroll
        for (int x = 0; x < 32; ++x) s += part[t][x];
        g_q[row0 + t] = s;
    }
}

// ---------------- r_c = mean_c . Pm_c ----------------
__global__ __launch_bounds__(256) void k_r() {
    int w = blockIdx.x * 4 + (threadIdx.x >> 6);   // 128 blocks -> 512 waves
    int lane = threadIdx.x & 63;
    float2 xa = ((const float2*)(g_mean + (size_t)w * DNUM))[lane];
    float2 pa = ((const float2*)(g_Pm + (size_t)w * DNUM))[lane];
    float v = xa.x * pa.x + xa.y * pa.y;
    #pragma unroll
    for (int off = 32; off > 0; off >>= 1) v += __shfl_down(v, off);
    if (lane == 0) g_r[w] = v;
}

// ---------------- out[b][c] = lp[c] - 0.5*q_b - 0.5*r_c + z_b . Pm_c ----------------
__global__ __launch_bounds__(256) void k_out(const float* __restrict__ z, float* __restrict__ out) {
    __shared__ float zs[64][65];
    __shared__ float ps[64][65];
    int t = threadIdx.x;
    int m0 = blockIdx.y * 64;      // sample rows
    int c0 = blockIdx.x * 64;      // class cols
    int tx = t & 15, ty = t >> 4;
    float acc[4][4] = {};
    for (int kc = 0; kc < 2; ++kc) {
        #pragma unroll
        for (int v = 0; v < 4; ++v) {
            int idx = t + v * 256;
            int r = idx >> 4, f4 = idx & 15;
            float4 zv = ((const float4*)z)[(size_t)(m0 + r) * 32 + kc * 16 + f4];
            zs[r][f4 * 4 + 0] = zv.x; zs[r][f4 * 4 + 1] = zv.y;
            zs[r][f4 * 4 + 2] = zv.z; zs[r][f4 * 4 + 3] = zv.w;
            float4 pv = ((const float4*)g_Pm)[(size_t)(c0 + r) * 32 + kc * 16 + f4];
            ps[r][f4 * 4 + 0] = pv.x; ps[r][f4 * 4 + 1] = pv.y;
            ps[r][f4 * 4 + 2] = pv.z; ps[r][f4 * 4 + 3] = pv.w;
        }
        __syncthreads();
        #pragma unroll 8
        for (int kk = 0; kk < 64; ++kk) {
            float za[4], pb[4];
            #pragma unroll
            for (int i = 0; i < 4; ++i) za[i] = zs[ty * 4 + i][kk];
            #pragma unroll
            for (int j = 0; j < 4; ++j) pb[j] = ps[tx * 4 + j][kk];
            #pragma unroll
            for (int i = 0; i < 4; ++i)
                #pragma unroll
                for (int j = 0; j < 4; ++j)
                    acc[i][j] += za[i] * pb[j];
        }
        __syncthreads();
    }
    int cbase = c0 + tx * 4;
    float4 lp4 = *(const float4*)(g_lp + cbase);
    float4 rv4 = *(const float4*)(g_r + cbase);
    #pragma unroll
    for (int i = 0; i < 4; ++i) {
        int row = m0 + ty * 4 + i;
        float qv = g_q[row];
        float4 o;
        o.x = acc[i][0] + lp4.x - 0.5f * (qv + rv4.x);
        o.y = acc[i][1] + lp4.y - 0.5f * (qv + rv4.y);
        o.z = acc[i][2] + lp4.z - 0.5f * (qv + rv4.z);
        o.w = acc[i][3] + lp4.w - 0.5f * (qv + rv4.w);
        *(float4*)&out[(size_t)row * CNUM + cbase] = o;
    }
}

extern "C" void kernel_launch(void* const* d_in, const int* in_sizes, int n_in,
                              void* d_out, int out_size, void* d_ws, size_t ws_size,
                              hipStream_t stream) {
    const float* z = (const float*)d_in[0];
    const int* y = (const int*)d_in[1];
    float* out = (float*)d_out;
    const int B = in_sizes[0] / DNUM;                 // 4096
    const float total = (float)B + (float)CNUM * EPSV;
    const float logtot = logf(total);

    k_zero<<<(CNUM * DNUM / 4 + 255) / 256, 256, 0, stream>>>();
    k_count_sum<<<B * 32 / 256, 256, 0, stream>>>(z, y, B);
    k_mean_prior<<<(CNUM * DNUM) / 256, 256, 0, stream>>>(logtot);
    k_gram<<<B / 128, 256, 0, stream>>>(z, y);
    k_finalize<<<(DNUM * DNUM) / 256, 256, 0, stream>>>(0.5f / total);
    k_inv<<<1, 1024, 0, stream>>>();
    k_matP<<<CNUM / 64, 256, 0, stream>>>();
    k_q<<<B / 64, 256, 0, stream>>>(z);
    k_r<<<CNUM / 4, 256, 0, stream>>>();
    k_out<<<dim3(CNUM / 64, B / 64), 256, 0, stream>>>(z, out);
}

// Round 5
// 243.750 us; speedup vs baseline: 2.3284x; 2.3284x over previous
//
#include <hip/hip_runtime.h>
#include <cmath>

#define CNUM 512
#define DNUM 128
#define BNUM 4096
#define EPSV 1e-5f

// ---- all intermediates in device globals: no d_ws dependence at all ----
__device__ float g_counts[CNUM];
__device__ float g_mean[CNUM * DNUM];
__device__ float g_lp[CNUM];
__device__ float g_G[DNUM * DNUM];
__device__ float g_P[DNUM * DNUM];
__device__ float g_Pm[CNUM * DNUM];
__device__ float g_r[CNUM];
__device__ float g_q[BNUM];

// ---------------- zero the accumulated buffers (every call) ----------------
__global__ __launch_bounds__(256) void k_zero() {
    int idx = blockIdx.x * 256 + threadIdx.x;
    if (idx < CNUM / 4) ((float4*)g_counts)[idx] = make_float4(0, 0, 0, 0);
    if (idx < CNUM * DNUM / 4) ((float4*)g_mean)[idx] = make_float4(0, 0, 0, 0);
    if (idx < DNUM * DNUM / 4) ((float4*)g_G)[idx] = make_float4(0, 0, 0, 0);
}

// ---------------- counts + per-class sums (atomics) ----------------
__global__ __launch_bounds__(256) void k_count_sum(const float* __restrict__ z, const int* __restrict__ y, int B) {
    int g = blockIdx.x * 256 + threadIdx.x;
    if (g >= B * 32) return;
    int b = g >> 5, c4 = g & 31;
    int yy = y[b];
    float4 zv = ((const float4*)z)[(size_t)b * 32 + c4];
    float* dst = g_mean + (size_t)yy * DNUM + c4 * 4;
    atomicAdd(dst + 0, zv.x);
    atomicAdd(dst + 1, zv.y);
    atomicAdd(dst + 2, zv.z);
    atomicAdd(dst + 3, zv.w);
    if (c4 == 0) atomicAdd(g_counts + yy, 1.0f);
}

// ---------------- mean = sum/(n+eps); logprior ----------------
__global__ __launch_bounds__(256) void k_mean_prior(float logtot) {
    int idx = blockIdx.x * 256 + threadIdx.x;   // 65536 threads
    int c = idx >> 7;
    float cnt = g_counts[c] + EPSV;
    g_mean[idx] = g_mean[idx] / cnt;
    if (idx < CNUM) g_lp[idx] = logf(g_counts[idx] + EPSV) - logtot;
}

// ---------------- G = sum_b dz dz^T (split over blocks, atomic partials) ----------------
__global__ __launch_bounds__(256) void k_gram(const float* __restrict__ z, const int* __restrict__ y) {
    __shared__ float dzs[16][132];
    int tx = threadIdx.x & 15, ty = threadIdx.x >> 4;
    float acc[8][8] = {};
    int b0 = blockIdx.x * 128;
    for (int ch = 0; ch < 8; ++ch) {
        int gb = b0 + ch * 16 + ty;
        int yy = y[gb];
        const float4* zp = (const float4*)(z + (size_t)gb * DNUM + tx * 8);
        const float4* mp = (const float4*)(g_mean + (size_t)yy * DNUM + tx * 8);
        float4 a0 = zp[0], a1 = zp[1], m0 = mp[0], m1 = mp[1];
        float* drow = &dzs[ty][tx * 8];
        drow[0] = a0.x - m0.x; drow[1] = a0.y - m0.y; drow[2] = a0.z - m0.z; drow[3] = a0.w - m0.w;
        drow[4] = a1.x - m1.x; drow[5] = a1.y - m1.y; drow[6] = a1.z - m1.z; drow[7] = a1.w - m1.w;
        __syncthreads();
        #pragma unroll
        for (int s = 0; s < 16; ++s) {
            const float4* pa = (const float4*)&dzs[s][ty * 8];
            const float4* pb = (const float4*)&dzs[s][tx * 8];
            float4 t0 = pa[0], t1 = pa[1];
            float4 u0 = pb[0], u1 = pb[1];
            float va[8] = {t0.x, t0.y, t0.z, t0.w, t1.x, t1.y, t1.z, t1.w};
            float vb[8] = {u0.x, u0.y, u0.z, u0.w, u1.x, u1.y, u1.z, u1.w};
            #pragma unroll
            for (int i = 0; i < 8; ++i)
                #pragma unroll
                for (int j = 0; j < 8; ++j)
                    acc[i][j] += va[i] * vb[j];
        }
        __syncthreads();
    }
    #pragma unroll
    for (int i = 0; i < 8; ++i)
        #pragma unroll
        for (int j = 0; j < 8; ++j)
            atomicAdd(&g_G[(size_t)(ty * 8 + i) * DNUM + tx * 8 + j], acc[i][j]);
}

// ---- register-tile Gauss-Jordan inverse (fused symmetrize+eps load) ----
// 256 threads; thread (ty,tx) owns 8x8 tile rows R..R+7, cols Cc..Cc+7 in VGPRs.
// Per pivot k: publish new col k (scaled) + old row k to LDS (k-slot zeroed so
// rank-1 leaves row/col k intact), 2 barriers, 64 reg FMAs/thread.
// Hazards verified: publish order (col-update skips a[ko][ko]; row publish reads
// a[ko][j!=ko]); dsh WAR separated by both barriers; compile-time ko avoids
// dynamic register indexing. No pivoting (SPD, cond~2 by Marchenko-Pastur).
__global__ __launch_bounds__(256) void k_gj(float invtot2) {
    __shared__ float rowk[128], colk[128];
    __shared__ float dsh;
    const int tx = threadIdx.x & 15, ty = threadIdx.x >> 4;
    const int R = ty * 8, Cc = tx * 8;
    float a[8][8];
    #pragma unroll
    for (int i = 0; i < 8; ++i)
        #pragma unroll
        for (int j = 0; j < 8; ++j) {
            int gi = R + i, gj = Cc + j;
            float v = (g_G[gi * DNUM + gj] + g_G[gj * DNUM + gi]) * invtot2;
            if (gi == gj) v += EPSV;
            a[i][j] = v;
        }
    if (tx == 0 && ty == 0) dsh = 1.0f / a[0][0];
    __syncthreads();
    for (int kb = 0; kb < 16; ++kb) {
        #pragma unroll
        for (int ko = 0; ko < 8; ++ko) {
            const int k = kb * 8 + ko;
            float d = dsh;
            if (tx == kb) {                        // new column k: A'[i][k] = -A[i][k]*d
                float cv[8];
                #pragma unroll
                for (int i = 0; i < 8; ++i) {
                    int gi = R + i;
                    float v = -a[i][ko] * d;
                    if (gi == k) v = 0.0f;         // mask pivot slot
                    cv[i] = v;
                    if (gi != k) a[i][ko] = v;
                }
                *(float4*)&colk[R]     = make_float4(cv[0], cv[1], cv[2], cv[3]);
                *(float4*)&colk[R + 4] = make_float4(cv[4], cv[5], cv[6], cv[7]);
            }
            if (ty == kb) {                        // old row k (pivot slot zeroed)
                float rv[8];
                #pragma unroll
                for (int j = 0; j < 8; ++j) {
                    int gj = Cc + j;
                    rv[j] = (gj == k) ? 0.0f : a[ko][j];
                }
                *(float4*)&rowk[Cc]     = make_float4(rv[0], rv[1], rv[2], rv[3]);
                *(float4*)&rowk[Cc + 4] = make_float4(rv[4], rv[5], rv[6], rv[7]);
            }
            __syncthreads();
            float4 c0 = *(const float4*)&colk[R], c1 = *(const float4*)&colk[R + 4];
            float4 r0 = *(const float4*)&rowk[Cc], r1 = *(const float4*)&rowk[Cc + 4];
            float cr[8] = {c0.x, c0.y, c0.z, c0.w, c1.x, c1.y, c1.z, c1.w};
            float rr[8] = {r0.x, r0.y, r0.z, r0.w, r1.x, r1.y, r1.z, r1.w};
            #pragma unroll
            for (int i = 0; i < 8; ++i)
                #pragma unroll
                for (int j = 0; j < 8; ++j)
                    a[i][j] += cr[i] * rr[j];
            if (ty == kb) {                        // scale row k (untouched by rank-1)
                #pragma unroll
                for (int j = 0; j < 8; ++j) { int gj = Cc + j; if (gj != k) a[ko][j] *= d; }
                if (tx == kb) a[ko][ko] = d;
            }
            if (ko < 7) { if (ty == kb && tx == kb) dsh = 1.0f / a[ko + 1][ko + 1]; }
            else        { if (kb < 15 && ty == kb + 1 && tx == kb + 1) dsh = 1.0f / a[0][0]; }
            __syncthreads();
        }
    }
    #pragma unroll
    for (int i = 0; i < 8; ++i) {
        *(float4*)(g_P + (size_t)(R + i) * DNUM + Cc)     = make_float4(a[i][0], a[i][1], a[i][2], a[i][3]);
        *(float4*)(g_P + (size_t)(R + i) * DNUM + Cc + 4) = make_float4(a[i][4], a[i][5], a[i][6], a[i][7]);
    }
}

// ---------------- Pm = mean @ P, fused r_c = mean_c . Pm_c ----------------
__global__ __launch_bounds__(256) void k_matPr() {
    __shared__ float xs[64][132];
    __shared__ float part[64][33];
    int t = threadIdx.x;
    int row0 = blockIdx.x * 64;
    #pragma unroll
    for (int v = 0; v < 8; ++v) {
        int idx = t + v * 256;
        int r = idx >> 5, f4 = idx & 31;
        float4 val = ((const float4*)g_mean)[(size_t)(row0 + r) * 32 + f4];
        *(float4*)&xs[r][f4 * 4] = val;
    }
    __syncthreads();
    int tx = t & 31, ty = t >> 5;                 // cols tx*4, rows ty*8
    float acc[8][4] = {};
    for (int e = 0; e < DNUM; ++e) {
        float4 pv = ((const float4*)g_P)[e * 32 + tx];
        #pragma unroll
        for (int i = 0; i < 8; ++i) {
            float xv = xs[ty * 8 + i][e];
            acc[i][0] += xv * pv.x; acc[i][1] += xv * pv.y;
            acc[i][2] += xv * pv.z; acc[i][3] += xv * pv.w;
        }
    }
    #pragma unroll
    for (int i = 0; i < 8; ++i) {
        int r = ty * 8 + i;
        *(float4*)&g_Pm[(size_t)(row0 + r) * DNUM + tx * 4] =
            make_float4(acc[i][0], acc[i][1], acc[i][2], acc[i][3]);
        part[r][tx] = acc[i][0] * xs[r][tx * 4 + 0] + acc[i][1] * xs[r][tx * 4 + 1]
                    + acc[i][2] * xs[r][tx * 4 + 2] + acc[i][3] * xs[r][tx * 4 + 3];
    }
    __syncthreads();
    if (t < 64) {
        float s = 0.f;
        #pragma unroll
        for (int x = 0; x < 32; ++x) s += part[t][x];
        g_r[row0 + t] = s;
    }
}

// ---------------- q_b = z_b . (P z_b), fused X@P + row-dot ----------------
__global__ __launch_bounds__(256) void k_q(const float* __restrict__ X) {
    __shared__ float xs[64][132];
    __shared__ float part[64][33];
    int t = threadIdx.x;
    int row0 = blockIdx.x * 64;
    #pragma unroll
    for (int v = 0; v < 8; ++v) {
        int idx = t + v * 256;
        int r = idx >> 5, f4 = idx & 31;
        float4 val = ((const float4*)X)[(size_t)(row0 + r) * 32 + f4];
        *(float4*)&xs[r][f4 * 4] = val;
    }
    __syncthreads();
    int tx = t & 31, ty = t >> 5;
    float acc[8][4] = {};
    for (int e = 0; e < DNUM; ++e) {
        float4 pv = ((const float4*)g_P)[e * 32 + tx];
        #pragma unroll
        for (int i = 0; i < 8; ++i) {
            float xv = xs[ty * 8 + i][e];
            acc[i][0] += xv * pv.x; acc[i][1] += xv * pv.y;
            acc[i][2] += xv * pv.z; acc[i][3] += xv * pv.w;
        }
    }
    #pragma unroll
    for (int i = 0; i < 8; ++i) {
        int r = ty * 8 + i;
        float s = acc[i][0] * xs[r][tx * 4 + 0] + acc[i][1] * xs[r][tx * 4 + 1]
                + acc[i][2] * xs[r][tx * 4 + 2] + acc[i][3] * xs[r][tx * 4 + 3];
        part[r][tx] = s;
    }
    __syncthreads();
    if (t < 64) {
        float s = 0.f;
        #pragma unroll
        for (int x = 0; x < 32; ++x) s += part[t][x];
        g_q[row0 + t] = s;
    }
}

// ---------------- out[b][c] = lp[c] - 0.5*q_b - 0.5*r_c + z_b . Pm_c ----------------
__global__ __launch_bounds__(256) void k_out(const float* __restrict__ z, float* __restrict__ out) {
    __shared__ float zs[64][65];
    __shared__ float ps[64][65];
    int t = threadIdx.x;
    int m0 = blockIdx.y * 64;      // sample rows
    int c0 = blockIdx.x * 64;      // class cols
    int tx = t & 15, ty = t >> 4;
    float acc[4][4] = {};
    for (int kc = 0; kc < 2; ++kc) {
        #pragma unroll
        for (int v = 0; v < 4; ++v) {
            int idx = t + v * 256;
            int r = idx >> 4, f4 = idx & 15;
            float4 zv = ((const float4*)z)[(size_t)(m0 + r) * 32 + kc * 16 + f4];
            zs[r][f4 * 4 + 0] = zv.x; zs[r][f4 * 4 + 1] = zv.y;
            zs[r][f4 * 4 + 2] = zv.z; zs[r][f4 * 4 + 3] = zv.w;
            float4 pv = ((const float4*)g_Pm)[(size_t)(c0 + r) * 32 + kc * 16 + f4];
            ps[r][f4 * 4 + 0] = pv.x; ps[r][f4 * 4 + 1] = pv.y;
            ps[r][f4 * 4 + 2] = pv.z; ps[r][f4 * 4 + 3] = pv.w;
        }
        __syncthreads();
        #pragma unroll 8
        for (int kk = 0; kk < 64; ++kk) {
            float za[4], pb[4];
            #pragma unroll
            for (int i = 0; i < 4; ++i) za[i] = zs[ty * 4 + i][kk];
            #pragma unroll
            for (int j = 0; j < 4; ++j) pb[j] = ps[tx * 4 + j][kk];
            #pragma unroll
            for (int i = 0; i < 4; ++i)
                #pragma unroll
                for (int j = 0; j < 4; ++j)
                    acc[i][j] += za[i] * pb[j];
        }
        __syncthreads();
    }
    int cbase = c0 + tx * 4;
    float4 lp4 = *(const float4*)(g_lp + cbase);
    float4 rv4 = *(const float4*)(g_r + cbase);
    #pragma unroll
    for (int i = 0; i < 4; ++i) {
        int row = m0 + ty * 4 + i;
        float qv = g_q[row];
        float4 o;
        o.x = acc[i][0] + lp4.x - 0.5f * (qv + rv4.x);
        o.y = acc[i][1] + lp4.y - 0.5f * (qv + rv4.y);
        o.z = acc[i][2] + lp4.z - 0.5f * (qv + rv4.z);
        o.w = acc[i][3] + lp4.w - 0.5f * (qv + rv4.w);
        *(float4*)&out[(size_t)row * CNUM + cbase] = o;
    }
}

extern "C" void kernel_launch(void* const* d_in, const int* in_sizes, int n_in,
                              void* d_out, int out_size, void* d_ws, size_t ws_size,
                              hipStream_t stream) {
    const float* z = (const float*)d_in[0];
    const int* y = (const int*)d_in[1];
    float* out = (float*)d_out;
    const int B = in_sizes[0] / DNUM;                 // 4096
    const float total = (float)B + (float)CNUM * EPSV;
    const float logtot = logf(total);

    k_zero<<<(CNUM * DNUM / 4 + 255) / 256, 256, 0, stream>>>();
    k_count_sum<<<B * 32 / 256, 256, 0, stream>>>(z, y, B);
    k_mean_prior<<<(CNUM * DNUM) / 256, 256, 0, stream>>>(logtot);
    k_gram<<<B / 128, 256, 0, stream>>>(z, y);
    k_gj<<<1, 256, 0, stream>>>(0.5f / total);
    k_matPr<<<CNUM / 64, 256, 0, stream>>>();
    k_q<<<B / 64, 256, 0, stream>>>(z);
    k_out<<<dim3(CNUM / 64, B / 64), 256, 0, stream>>>(z, out);
}